// Round 1
// baseline (229.782 us; speedup 1.0000x reference)
//
#include <hip/hip_runtime.h>

#define BATCH 65536
#define STEPS 200
#define NPOP 100000.0f
#define CLAMP_V 100000.0f
#define H_STEP 0.5f

__global__ __launch_bounds__(256) void seir_kernel(
    const float* __restrict__ init,
    const float* __restrict__ w,
    float* __restrict__ out)
{
    const int b = blockIdx.x * blockDim.x + threadIdx.x;
    if (b >= BATCH) return;

    const float A = w[4];
    const float B = w[5];
    const float C = w[6];
    const float invN = 1.0f / NPOP;

    float4 x = reinterpret_cast<const float4*>(init)[b];
    float4* o = reinterpret_cast<float4*>(out) + (size_t)b * STEPS;

    // Unroll 4 so the four 16B stores covering one 64B cache line issue
    // back-to-back (helps L2 write-combining of the strided pattern).
    #pragma unroll 4
    for (int t = 0; t < STEPS; ++t) {
        float infl = B * x.x * (x.y + x.z) * invN;
        float ae = A * x.y;
        float ci = C * x.z;
        float d0 = -infl;
        float d1 = infl - ae;
        float d2 = ae - ci;
        float d3 = ci;
        d0 = fminf(fmaxf(d0, -CLAMP_V), CLAMP_V);
        d1 = fminf(fmaxf(d1, -CLAMP_V), CLAMP_V);
        d2 = fminf(fmaxf(d2, -CLAMP_V), CLAMP_V);
        d3 = fminf(fmaxf(d3, -CLAMP_V), CLAMP_V);
        x.x += H_STEP * d0;
        x.y += H_STEP * d1;
        x.z += H_STEP * d2;
        x.w += H_STEP * d3;
        o[t] = x;
    }
}

extern "C" void kernel_launch(void* const* d_in, const int* in_sizes, int n_in,
                              void* d_out, int out_size, void* d_ws, size_t ws_size,
                              hipStream_t stream) {
    const float* init = (const float*)d_in[0];
    const float* w    = (const float*)d_in[1];
    float* out        = (float*)d_out;

    seir_kernel<<<dim3(BATCH / 256), dim3(256), 0, stream>>>(init, w, out);
}

// Round 2
// 204.676 us; speedup vs baseline: 1.1227x; 1.1227x over previous
//
#include <hip/hip_runtime.h>

#define BATCH   65536
#define STEPS   200
#define TCHUNK  8
#define NCHUNK  (STEPS / TCHUNK)   // 25
#define BLK     64                 // one wave per block
#define LSTRIDE 33                 // 8 float4 = 32 dwords + 1 pad dword

__global__ __launch_bounds__(BLK) void seir_kernel(
    const float* __restrict__ init,
    const float* __restrict__ w,
    float* __restrict__ out)
{
    __shared__ float lds[BLK * LSTRIDE];

    const int lane   = threadIdx.x;          // 0..63
    const int base_b = blockIdx.x * BLK;     // first batch element of this block
    const int b      = base_b + lane;

    const float A = w[4];
    const float B = w[5];
    const float C = w[6];
    const float invN = 1.0f / 100000.0f;

    float4 x = reinterpret_cast<const float4*>(init)[b];
    float4* outf4 = reinterpret_cast<float4*>(out);

    for (int chunk = 0; chunk < NCHUNK; ++chunk) {
        // ---- compute TCHUNK steps, stash each new state in LDS ----
        // LDS write banks: (lane*33 + tt*4 + c) % 32 = (lane + 4*tt + c) % 32
        // -> exactly 2 lanes/bank (lane, lane+32): free.
        #pragma unroll
        for (int tt = 0; tt < TCHUNK; ++tt) {
            float infl = B * x.x * (x.y + x.z) * invN;
            float ae = A * x.y;
            float ci = C * x.z;
            float d0 = -infl;
            float d1 = infl - ae;
            float d2 = ae - ci;
            float d3 = ci;
            d0 = fminf(fmaxf(d0, -100000.0f), 100000.0f);
            d1 = fminf(fmaxf(d1, -100000.0f), 100000.0f);
            d2 = fminf(fmaxf(d2, -100000.0f), 100000.0f);
            d3 = fminf(fmaxf(d3, -100000.0f), 100000.0f);
            x.x += 0.5f * d0;
            x.y += 0.5f * d1;
            x.z += 0.5f * d2;
            x.w += 0.5f * d3;
            const int a = lane * LSTRIDE + tt * 4;
            lds[a + 0] = x.x;
            lds[a + 1] = x.y;
            lds[a + 2] = x.z;
            lds[a + 3] = x.w;
        }
        __syncthreads();

        // ---- coalesced flush: 512 float4 per chunk, 8 per lane ----
        // Lane group of 8 covers one batch element's 8 consecutive float4
        // (128 B contiguous) -> each store instr writes 16 FULL 64B lines.
        const int t0 = chunk * TCHUNK;
        #pragma unroll
        for (int k = 0; k < 8; ++k) {
            const int s  = k * BLK + lane;
            const int bb = s >> 3;     // batch element within block (0..63)
            const int j  = s & 7;      // timestep within chunk
            const int a  = bb * LSTRIDE + j * 4;
            float4 v = make_float4(lds[a + 0], lds[a + 1], lds[a + 2], lds[a + 3]);
            outf4[(size_t)(base_b + bb) * STEPS + t0 + j] = v;
        }
        __syncthreads();   // protect LDS reuse by next chunk
    }
}

extern "C" void kernel_launch(void* const* d_in, const int* in_sizes, int n_in,
                              void* d_out, int out_size, void* d_ws, size_t ws_size,
                              hipStream_t stream) {
    const float* init = (const float*)d_in[0];
    const float* w    = (const float*)d_in[1];
    float* out        = (float*)d_out;

    seir_kernel<<<dim3(BATCH / BLK), dim3(BLK), 0, stream>>>(init, w, out);
}